// Round 10
// baseline (199.981 us; speedup 1.0000x reference)
//
#include <hip/hip_runtime.h>
#include <hip/hip_bf16.h>

#define T_LEN  2048
#define NHEAD  16
#define HDIM   64
#define DMODEL 1024
#define BATCH  2
#define MROWS  4096   // B*T
#define L_CHK  64
#define N_CHK  (T_LEN / L_CHK)   // 32
#define BH     (BATCH * NHEAD)   // 32
#define LSTR   72                // padded LDS row stride (shorts); 144B = 16B-mult

typedef __attribute__((ext_vector_type(8))) short short8;
typedef __attribute__((ext_vector_type(4))) float f32x4;
typedef __attribute__((ext_vector_type(4))) unsigned short ushort4v;

// async global->LDS, 16B per lane; LDS dest = wave-uniform base + lane*16
#define GLDS(GP, LP) __builtin_amdgcn_global_load_lds( \
    (__attribute__((address_space(1))) void*)(void*)(GP), \
    (__attribute__((address_space(3))) void*)(LP), 16, 0, 0)

__device__ __forceinline__ unsigned short f2bf(float f) {
  union { float f; unsigned int u; } v; v.f = f;
  unsigned int r = v.u + 0x7FFFu + ((v.u >> 16) & 1u);   // RNE
  return (unsigned short)(r >> 16);
}
__device__ __forceinline__ float bf2f(short s) {
  union { unsigned int u; float f; } v;
  v.u = ((unsigned int)(unsigned short)s) << 16;
  return v.f;
}

// ---------------------------------------------------------------------------
// Weight transposes + x conversion in one launch: grid (16,16,5).
// ---------------------------------------------------------------------------
__global__ __launch_bounds__(256) void ha_conv(
    const float* __restrict__ Wq, const float* __restrict__ Wa,
    const float* __restrict__ Wb, const float* __restrict__ Wo,
    const float* __restrict__ X,
    short* __restrict__ wqabT, short* __restrict__ woT,
    short* __restrict__ Xb) {
  const int z = blockIdx.z;
  const int tid = threadIdx.x;
  if (z == 4) {   // x conversion: 256 blocks x 16384 floats
    const int bidl = blockIdx.y * 16 + blockIdx.x;
    #pragma unroll
    for (int p = 0; p < 8; ++p) {
      const size_t idx = (size_t)bidl * 16384 + (size_t)p * 2048 + tid * 8;
      float4 v0 = *(const float4*)(X + idx);
      float4 v1 = *(const float4*)(X + idx + 4);
      short8 o;
      o[0] = (short)f2bf(v0.x); o[1] = (short)f2bf(v0.y);
      o[2] = (short)f2bf(v0.z); o[3] = (short)f2bf(v0.w);
      o[4] = (short)f2bf(v1.x); o[5] = (short)f2bf(v1.y);
      o[6] = (short)f2bf(v1.z); o[7] = (short)f2bf(v1.w);
      *(short8*)(Xb + idx) = o;
    }
    return;
  }
  __shared__ float tile[64][65];
  const float* W = (z == 0) ? Wq : (z == 1) ? Wa : (z == 2) ? Wb : Wo;
  short* WT = (z < 3) ? wqabT + (size_t)z * 1024 * DMODEL : woT;
  const int k0 = blockIdx.y * 64, n0 = blockIdx.x * 64;
  #pragma unroll
  for (int p = 0; p < 4; ++p) {
    const int r  = p * 16 + (tid >> 4);
    const int c4 = (tid & 15) * 4;
    float4 v = *(const float4*)(W + (size_t)(k0 + r) * DMODEL + n0 + c4);
    tile[r][c4 + 0] = v.x; tile[r][c4 + 1] = v.y;
    tile[r][c4 + 2] = v.z; tile[r][c4 + 3] = v.w;
  }
  __syncthreads();
  #pragma unroll
  for (int p = 0; p < 4; ++p) {
    const int n = p * 16 + (tid >> 4);
    const int c = (tid & 15) * 4;
    ushort4v o = { f2bf(tile[c + 0][n]), f2bf(tile[c + 1][n]),
                   f2bf(tile[c + 2][n]), f2bf(tile[c + 3][n]) };
    *(ushort4v*)(WT + (size_t)(n0 + n) * DMODEL + k0 + c) = o;
  }
}

// ---------------------------------------------------------------------------
// Fused QAB projection GEMM + per-head LayerNorm epilogue, bf16 out.
// Linear LDS layout (r5-proven). Epilogue: normalize acc in place, restage
// via padded LDS (stride 136), 4x16B stores/thread (r9 bug: was 2x16B ->
// half the columns unwritten; 256 thr x 32 shorts = 8192 = full 64x128 half).
// ---------------------------------------------------------------------------
__global__ __launch_bounds__(256) void ha_gemm_qab(
    const short* __restrict__ Ab, const short* __restrict__ Bt,
    short* __restrict__ q, short* __restrict__ a, short* __restrict__ bOut,
    const float* __restrict__ qg, const float* __restrict__ qbet,
    const float* __restrict__ ag, const float* __restrict__ abet,
    const float* __restrict__ bg, const float* __restrict__ bbet) {
  __shared__ short As[128 * 32] __attribute__((aligned(16)));
  __shared__ short Bs[128 * 32] __attribute__((aligned(16)));
  __shared__ short Stg[64 * 136] __attribute__((aligned(16)));   // 17 KB stage
  const int tid = threadIdx.x;
  const int wave = tid >> 6, lane = tid & 63;
  const int m0  = blockIdx.y * 128;
  const int n0g = blockIdx.x * 128;           // [0, 3072)
  short* Cbuf; const float* gamma; const float* beta;
  if (n0g < 1024)      { Cbuf = q;    gamma = qg; beta = qbet; }
  else if (n0g < 2048) { Cbuf = a;    gamma = ag; beta = abet; }
  else                 { Cbuf = bOut; gamma = bg; beta = bbet; }
  const int n0 = n0g & 1023;

  const int srow = wave * 32 + (lane >> 2);
  const int scol = (lane & 3) * 8;
  const short* agp = Ab + (size_t)(m0 + srow) * DMODEL + scol;
  const short* bgp = Bt + (size_t)(n0g + srow) * DMODEL + scol;
  short* alp = As + wave * 32 * 32;
  short* blp = Bs + wave * 32 * 32;

  f32x4 acc[4][4] = {};
  const int lm = lane & 15, kh = lane >> 4;
  const int wm = (wave >> 1) * 64, wn = (wave & 1) * 64;

  float gl[4], bl[4];
  #pragma unroll
  for (int j = 0; j < 4; ++j) {
    gl[j] = gamma[j * 16 + lm];
    bl[j] = beta[j * 16 + lm];
  }

  for (int k0 = 0; k0 < DMODEL; k0 += 32) {
    GLDS(agp,               alp);
    GLDS(agp + 16 * DMODEL, alp + 16 * 32);
    GLDS(bgp,               blp);
    GLDS(bgp + 16 * DMODEL, blp + 16 * 32);
    agp += 32; bgp += 32;
    __syncthreads();
    short8 af[4], bf[4];
    #pragma unroll
    for (int i = 0; i < 4; ++i) {
      af[i] = *(const short8*)&As[(wm + i * 16 + lm) * 32 + kh * 8];
      bf[i] = *(const short8*)&Bs[(wn + i * 16 + lm) * 32 + kh * 8];
    }
    #pragma unroll
    for (int i = 0; i < 4; ++i)
      #pragma unroll
      for (int j = 0; j < 4; ++j)
        acc[i][j] = __builtin_amdgcn_mfma_f32_16x16x32_bf16(
            af[i], bf[j], acc[i][j], 0, 0, 0);
    __syncthreads();
  }

  // ---- LayerNorm: normalize acc in place ----
  #pragma unroll
  for (int i = 0; i < 4; ++i) {
    float s1[4] = {0.f, 0.f, 0.f, 0.f};
    float s2[4] = {0.f, 0.f, 0.f, 0.f};
    #pragma unroll
    for (int j = 0; j < 4; ++j)
      #pragma unroll
      for (int r = 0; r < 4; ++r) {
        const float v = acc[i][j][r];
        s1[r] += v; s2[r] += v * v;
      }
    #pragma unroll
    for (int m = 1; m <= 8; m <<= 1)
      #pragma unroll
      for (int r = 0; r < 4; ++r) {
        s1[r] += __shfl_xor(s1[r], m);
        s2[r] += __shfl_xor(s2[r], m);
      }
    #pragma unroll
    for (int r = 0; r < 4; ++r) {
      const float mean = s1[r] * 0.015625f;
      const float var  = s2[r] * 0.015625f - mean * mean;
      const float rs   = rsqrtf(var + 1e-5f);
      #pragma unroll
      for (int j = 0; j < 4; ++j)
        acc[i][j][r] = (acc[i][j][r] - mean) * rs * gl[j] + bl[j];
    }
  }

  // ---- staged vectorized store, two m-half passes ----
  #pragma unroll
  for (int pass = 0; pass < 2; ++pass) {
    if (wm == pass * 64) {
      #pragma unroll
      for (int i = 0; i < 4; ++i)
        #pragma unroll
        for (int r = 0; r < 4; ++r)
          #pragma unroll
          for (int j = 0; j < 4; ++j)
            Stg[(i * 16 + kh * 4 + r) * 136 + wn + j * 16 + lm] =
                (short)f2bf(acc[i][j][r]);
    }
    __syncthreads();
    {
      const int row = tid >> 2, seg = tid & 3;   // 64 rows x 4 segs x 32 shorts
      const short* sp = &Stg[row * 136 + seg * 32];
      short8 v0 = *(const short8*)(sp);
      short8 v1 = *(const short8*)(sp + 8);
      short8 v2 = *(const short8*)(sp + 16);
      short8 v3 = *(const short8*)(sp + 24);
      short* cp = Cbuf + (size_t)(m0 + pass * 64 + row) * DMODEL + n0 + seg * 32;
      *(short8*)cp        = v0;
      *(short8*)(cp + 8)  = v1;
      *(short8*)(cp + 16) = v2;
      *(short8*)(cp + 24) = v3;
    }
    __syncthreads();
  }
}

// ---------------------------------------------------------------------------
// Output GEMM: C[M,1024] = Ob[M,1024](bf16) @ WoT[1024,1024]^T (linear LDS)
// ---------------------------------------------------------------------------
__global__ __launch_bounds__(256) void ha_gemm_out(
    const short* __restrict__ Ab, const short* __restrict__ Bt,
    float* __restrict__ C) {
  __shared__ short As[128 * 32] __attribute__((aligned(16)));
  __shared__ short Bs[64 * 32] __attribute__((aligned(16)));
  const int tid = threadIdx.x;
  const int wave = tid >> 6, lane = tid & 63;
  const int m0 = blockIdx.y * 128;
  const int n0 = blockIdx.x * 64;

  const int arow = wave * 32 + (lane >> 2);
  const int brow = wave * 16 + (lane >> 2);
  const int scol = (lane & 3) * 8;
  const short* agp = Ab + (size_t)(m0 + arow) * DMODEL + scol;
  const short* bgp = Bt + (size_t)(n0 + brow) * DMODEL + scol;
  short* alp = As + wave * 32 * 32;
  short* blp = Bs + wave * 16 * 32;

  f32x4 acc[4][2] = {};
  const int lm = lane & 15, kh = lane >> 4;
  const int wm = (wave >> 1) * 64, wn = (wave & 1) * 32;

  for (int k0 = 0; k0 < DMODEL; k0 += 32) {
    GLDS(agp,               alp);
    GLDS(agp + 16 * DMODEL, alp + 16 * 32);
    GLDS(bgp,               blp);
    agp += 32; bgp += 32;
    __syncthreads();
    short8 af[4], bf2[2];
    #pragma unroll
    for (int i = 0; i < 4; ++i)
      af[i] = *(const short8*)&As[(wm + i * 16 + lm) * 32 + kh * 8];
    #pragma unroll
    for (int j = 0; j < 2; ++j)
      bf2[j] = *(const short8*)&Bs[(wn + j * 16 + lm) * 32 + kh * 8];
    #pragma unroll
    for (int i = 0; i < 4; ++i)
      #pragma unroll
      for (int j = 0; j < 2; ++j)
        acc[i][j] = __builtin_amdgcn_mfma_f32_16x16x32_bf16(
            af[i], bf2[j], acc[i][j], 0, 0, 0);
    __syncthreads();
  }
  #pragma unroll
  for (int i = 0; i < 4; ++i)
    #pragma unroll
    for (int j = 0; j < 2; ++j) {
      float* cp = C + (size_t)(m0 + wm + i * 16 + kh * 4) * DMODEL +
                  n0 + wn + j * 16 + lm;
      #pragma unroll
      for (int r = 0; r < 4; ++r) cp[(size_t)r * DMODEL] = acc[i][j][r];
    }
}

// ---------------------------------------------------------------------------
// Scan pass 1 (MFMA): per (bh,c): Bt[e][s] staged transposed; L^T[d][s] =
// local-exclusive cumsum of a (bf16); M[e][d] = Bt·L^T via mfma (K=s).
// M written bf16 (s2p accumulates fp32). Also emits Asums/Bsums.
// ---------------------------------------------------------------------------
__global__ __launch_bounds__(256) void ha_scan1(
    const short* __restrict__ An, const short* __restrict__ Bn,
    short* __restrict__ M, float* __restrict__ Asums, float* __restrict__ Bsums) {
  __shared__ short Btl[64 * LSTR] __attribute__((aligned(16)));
  __shared__ short Ltl[64 * LSTR] __attribute__((aligned(16)));
  __shared__ float sega[4][64];
  __shared__ float segb[4][64];
  const int bid = blockIdx.x;
  const int c   = bid & (N_CHK - 1);
  const int bh  = bid >> 5;
  const int b = bh >> 4, h = bh & 15;
  const int tid = threadIdx.x;
  const size_t rowbase = ((size_t)b * T_LEN + (size_t)c * L_CHK) * DMODEL + h * HDIM;
  const size_t vec = ((size_t)bh * N_CHK + c) * 64;

  // stage B transposed: Btl[e][s]
  #pragma unroll
  for (int i = 0; i < 2; ++i) {
    const int idx = tid + 256 * i;
    const int s = idx >> 3, c8 = (idx & 7) * 8;
    short8 b8 = *(const short8*)(Bn + rowbase + (size_t)s * DMODEL + c8);
    #pragma unroll
    for (int k = 0; k < 8; ++k) Btl[(c8 + k) * LSTR + s] = b8[k];
  }

  const int d = tid & 63, seg = tid >> 6;
  {
    float run = 0.f;
    for (int s = seg * 16; s < seg * 16 + 16; ++s) {
      const float v = bf2f(An[rowbase + (size_t)s * DMODEL + d]);
      Ltl[d * LSTR + s] = (short)f2bf(run);
      run += v;
    }
    sega[seg][d] = run;
  }
  __syncthreads();
  {
    float off = 0.f;
    for (int qq = 0; qq < seg; ++qq) off += sega[qq][d];
    #pragma unroll
    for (int g = 0; g < 2; ++g) {
      short8 v = *(short8*)&Ltl[d * LSTR + seg * 16 + g * 8];
      #pragma unroll
      for (int k = 0; k < 8; ++k) v[k] = (short)f2bf(bf2f(v[k]) + off);
      *(short8*)&Ltl[d * LSTR + seg * 16 + g * 8] = v;
    }
    if (seg == 3) Asums[vec + d] = off + sega[3][d];
    float sb = 0.f;
    #pragma unroll
    for (int g = 0; g < 2; ++g) {
      short8 v = *(const short8*)&Btl[d * LSTR + seg * 16 + g * 8];
      #pragma unroll
      for (int k = 0; k < 8; ++k) sb += bf2f(v[k]);
    }
    segb[seg][d] = sb;
  }
  __syncthreads();
  if (tid < 64)
    Bsums[vec + tid] = segb[0][tid] + segb[1][tid] + segb[2][tid] + segb[3][tid];

  // M[e][d] = sum_s Btl[e][s] * Ltl[d][s]; wave owns 16-row e-strip
  const int wave = tid >> 6, lane = tid & 63;
  const int lm = lane & 15, quad = lane >> 4;
  const int estrip = wave * 16;
  f32x4 acc[4] = {};
  #pragma unroll
  for (int kk = 0; kk < 2; ++kk) {
    short8 afr = *(const short8*)&Btl[(estrip + lm) * LSTR + kk * 32 + quad * 8];
    #pragma unroll
    for (int j = 0; j < 4; ++j) {
      short8 bfr = *(const short8*)&Ltl[(j * 16 + lm) * LSTR + kk * 32 + quad * 8];
      acc[j] = __builtin_amdgcn_mfma_f32_16x16x32_bf16(afr, bfr, acc[j], 0, 0, 0);
    }
  }
  short* Mp = M + vec * 64;
  #pragma unroll
  for (int j = 0; j < 4; ++j)
    #pragma unroll
    for (int r = 0; r < 4; ++r)
      Mp[(estrip + quad * 4 + r) * 64 + j * 16 + lm] = (short)f2bf(acc[j][r]);
}

// ---------------------------------------------------------------------------
// Parallel S-prefix: Aoff prefix in LDS (part-0 exports), exclusive S prefix
// over chunks with depth-2 prefetch; M read bf16; Soff written bf16.
// ---------------------------------------------------------------------------
__global__ __launch_bounds__(256) void ha_s2p(
    const short* __restrict__ M, const float* __restrict__ Asums,
    const float* __restrict__ Bsums, float* __restrict__ Aoff,
    short* __restrict__ Soffb) {
  __shared__ float ao[N_CHK][64];   // 8 KB
  const int part = blockIdx.x & 7;
  const int bh   = blockIdx.x >> 3;
  const int tid  = threadIdx.x;
  for (int i = tid; i < N_CHK * 64; i += 256)
    ao[i >> 6][i & 63] = Asums[(size_t)bh * N_CHK * 64 + i];
  __syncthreads();
  if (tid < 64) {
    float run = 0.f;
    for (int c = 0; c < N_CHK; ++c) {
      const float v = ao[c][tid];
      ao[c][tid] = run;
      run += v;
    }
  }
  __syncthreads();
  if (part == 0)
    for (int i = tid; i < N_CHK * 64; i += 256)
      Aoff[(size_t)bh * N_CHK * 64 + i] = ao[i >> 6][i & 63];

  const int e = part * 8 + (tid >> 5);
  const int d = (tid & 31) * 2;
  float2 S = make_float2(0.f, 0.f);
  const short* Mp = M + (size_t)bh * N_CHK * 4096 + e * 64 + d;
  const float* Bp = Bsums + (size_t)bh * N_CHK * 64 + e;
  short* Sp = Soffb + (size_t)bh * N_CHK * 4096 + e * 64 + d;
  unsigned mr0 = *(const unsigned*)Mp;
  unsigned mr1 = *(const unsigned*)(Mp + 4096);
  float bs0 = Bp[0], bs1 = Bp[64];
  for (int c = 0; c < N_CHK; ++c) {
    const int c2 = (c + 2 < N_CHK) ? c + 2 : c;
    const unsigned mrn = *(const unsigned*)(Mp + (size_t)c2 * 4096);
    const float bsn = Bp[(size_t)c2 * 64];
    const unsigned pk = (unsigned)f2bf(S.x) | ((unsigned)f2bf(S.y) << 16);
    *(unsigned*)(Sp + (size_t)c * 4096) = pk;
    S.x += fmaf(bs0, ao[c][d],     bf2f((short)(mr0 & 0xffffu)));
    S.y += fmaf(bs0, ao[c][d + 1], bf2f((short)(mr0 >> 16)));
    mr0 = mr1; mr1 = mrn; bs0 = bs1; bs1 = bsn;
  }
}

// ---------------------------------------------------------------------------
// Scan pass 3 (MFMA): P = Q·G^T (bf16), causal mask, O = Pt·B^T + Q·Soff^T.
// O restaged through Gs (dead after P phase) -> 16B vector stores.
// ---------------------------------------------------------------------------
__global__ __launch_bounds__(256) void ha_scan3(
    const short* __restrict__ Qn, const short* __restrict__ An,
    const short* __restrict__ Bn, const short* __restrict__ Soffb,
    const float* __restrict__ Aoff, short* __restrict__ Ob) {
  __shared__ short Qs [64 * LSTR] __attribute__((aligned(16)));
  __shared__ short Gs [64 * LSTR] __attribute__((aligned(16)));
  __shared__ short Btl[64 * LSTR] __attribute__((aligned(16)));
  __shared__ short Ssl[64 * LSTR] __attribute__((aligned(16)));
  __shared__ short Ptl[64 * LSTR] __attribute__((aligned(16)));
  __shared__ float sega[4][64];
  const int bid = blockIdx.x;
  const int c   = bid & (N_CHK - 1);
  const int bh  = bid >> 5;
  const int b = bh >> 4, h = bh & 15;
  const int tid = threadIdx.x;
  const size_t rowbase = ((size_t)b * T_LEN + (size_t)c * L_CHK) * DMODEL + h * HDIM;
  const size_t vec = ((size_t)bh * N_CHK + c) * 64;

  #pragma unroll
  for (int i = 0; i < 2; ++i) {
    const int idx = tid + 256 * i;
    const int r = idx >> 3, c8 = (idx & 7) * 8;
    short8 q8 = *(const short8*)(Qn + rowbase + (size_t)r * DMODEL + c8);
    *(short8*)&Qs[r * LSTR + c8] = q8;
    short8 s8 = *(const short8*)(Soffb + vec * 64 + (size_t)r * 64 + c8);
    *(short8*)&Ssl[r * LSTR + c8] = s8;
    short8 b8 = *(const short8*)(Bn + rowbase + (size_t)r * DMODEL + c8);
    #pragma unroll
    for (int k = 0; k < 8; ++k) Btl[(c8 + k) * LSTR + r] = b8[k];
  }

  const int d = tid & 63, seg = tid >> 6;
  {
    float run = 0.f;
    for (int s = seg * 16; s < seg * 16 + 16; ++s) {
      const float v = bf2f(An[rowbase + (size_t)s * DMODEL + d]);
      Gs[s * LSTR + d] = (short)f2bf(run);
      run += v;
    }
    sega[seg][d] = run;
  }
  __syncthreads();
  {
    float off = Aoff[vec + d];
    for (int qq = 0; qq < seg; ++qq) off += sega[qq][d];
    for (int s = seg * 16; s < seg * 16 + 16; ++s)
      Gs[s * LSTR + d] = (short)f2bf(bf2f(Gs[s * LSTR + d]) + off);
  }
  __syncthreads();

  const int wave = tid >> 6, lane = tid & 63;
  const int lm = lane & 15, quad = lane >> 4;
  const int tstrip = wave * 16;
  {
    f32x4 p[4] = {};
    #pragma unroll
    for (int kk = 0; kk < 2; ++kk) {
      short8 qf = *(const short8*)&Qs[(tstrip + lm) * LSTR + kk * 32 + quad * 8];
      #pragma unroll
      for (int j = 0; j < 4; ++j) {
        short8 gf = *(const short8*)&Gs[(j * 16 + lm) * LSTR + kk * 32 + quad * 8];
        p[j] = __builtin_amdgcn_mfma_f32_16x16x32_bf16(qf, gf, p[j], 0, 0, 0);
      }
    }
    #pragma unroll
    for (int j = 0; j < 4; ++j)
      #pragma unroll
      for (int r = 0; r < 4; ++r) {
        const int t = tstrip + quad * 4 + r;
        const int s = j * 16 + lm;
        Ptl[t * LSTR + s] = (s <= t) ? (short)f2bf(p[j][r]) : (short)0;
      }
  }
  __syncthreads();

  {
    f32x4 o[4] = {};
    #pragma unroll
    for (int kk = 0; kk < 2; ++kk) {
      short8 pf = *(const short8*)&Ptl[(tstrip + lm) * LSTR + kk * 32 + quad * 8];
      #pragma unroll
      for (int j = 0; j < 4; ++j) {
        short8 bfr = *(const short8*)&Btl[(j * 16 + lm) * LSTR + kk * 32 + quad * 8];
        o[j] = __builtin_amdgcn_mfma_f32_16x16x32_bf16(pf, bfr, o[j], 0, 0, 0);
      }
    }
    #pragma unroll
    for (int kk = 0; kk < 2; ++kk) {
      short8 qf = *(const short8*)&Qs[(tstrip + lm) * LSTR + kk * 32 + quad * 8];
      #pragma unroll
      for (int j = 0; j < 4; ++j) {
        short8 sf = *(const short8*)&Ssl[(j * 16 + lm) * LSTR + kk * 32 + quad * 8];
        o[j] = __builtin_amdgcn_mfma_f32_16x16x32_bf16(qf, sf, o[j], 0, 0, 0);
      }
    }
    // restage O bf16 into Gs (free after P phase), [t][e]
    #pragma unroll
    for (int j = 0; j < 4; ++j)
      #pragma unroll
      for (int r = 0; r < 4; ++r)
        Gs[(tstrip + quad * 4 + r) * LSTR + j * 16 + lm] = (short)f2bf(o[j][r]);
  }
  __syncthreads();
  {
    const int t = tid >> 2, seg2 = tid & 3;   // 64 rows x 4 segs x 16 shorts = 64 cols
    short8 v0 = *(const short8*)&Gs[t * LSTR + seg2 * 16];
    short8 v1 = *(const short8*)&Gs[t * LSTR + seg2 * 16 + 8];
    short* op = Ob + rowbase + (size_t)t * DMODEL + seg2 * 16;
    *(short8*)op       = v0;
    *(short8*)(op + 8) = v1;
  }
}

// ---------------------------------------------------------------------------
extern "C" void kernel_launch(void* const* d_in, const int* in_sizes, int n_in,
                              void* d_out, int out_size, void* d_ws,
                              size_t ws_size, hipStream_t stream) {
  const float* x  = (const float*)d_in[0];
  const float* Wq = (const float*)d_in[1];
  const float* Wa = (const float*)d_in[2];
  const float* Wb = (const float*)d_in[3];
  const float* Wo = (const float*)d_in[4];
  const float* qg = (const float*)d_in[5];
  const float* qb = (const float*)d_in[6];
  const float* ag = (const float*)d_in[7];
  const float* ab = (const float*)d_in[8];
  const float* bg = (const float*)d_in[9];
  const float* bb = (const float*)d_in[10];
  float* out = (float*)d_out;

  // workspace layout (~50 MB of the 64 MB proven available):
  char* ws = (char*)d_ws;
  short* qn  = (short*)(ws);                          // [0,8) MB bf16
  short* an  = (short*)(ws + ((size_t)8  << 20));     // [8,16) MB
  short* bn  = (short*)(ws + ((size_t)16 << 20));     // [16,24) MB
  short* xb  = (short*)(ws + ((size_t)24 << 20));     // [24,32) MB
  short* obb = xb;                                    // overlay: xb dead after QAB GEMM
  short* wqabT = (short*)(ws + ((size_t)32 << 20));   // [32,38) MB
  short* woT   = (short*)(ws + ((size_t)38 << 20));   // [38,40) MB
  float* asums = (float*)(ws + ((size_t)40 << 20));   // 256 KB
  float* bsums = asums + (size_t)BH * N_CHK * 64;     // 256 KB
  float* aoff  = bsums + (size_t)BH * N_CHK * 64;     // 256 KB
  short* soffb = (short*)(ws + ((size_t)42 << 20));   // [42,50) MB bf16 Soff
  short* Mbuf  = (short*)out;  // d_out doubles as bf16 Mlocal scratch (8 MB)

  ha_conv<<<dim3(16, 16, 5), 256, 0, stream>>>(Wq, Wa, Wb, Wo, x,
                                               wqabT, woT, xb);

  ha_gemm_qab<<<dim3(24, 32), 256, 0, stream>>>(xb, wqabT, qn, an, bn,
                                                qg, qb, ag, ab, bg, bb);

  ha_scan1<<<BH * N_CHK, 256, 0, stream>>>(an, bn, Mbuf, asums, bsums);
  ha_s2p<<<BH * 8, 256, 0, stream>>>(Mbuf, asums, bsums, aoff, soffb);
  ha_scan3<<<BH * N_CHK, 256, 0, stream>>>(qn, an, bn, soffb, aoff, obb);

  ha_gemm_out<<<dim3(16, 32), 256, 0, stream>>>(obb, woT, out);
}

// Round 11
// 178.351 us; speedup vs baseline: 1.1213x; 1.1213x over previous
//
#include <hip/hip_runtime.h>
#include <hip/hip_bf16.h>

#define T_LEN  2048
#define NHEAD  16
#define HDIM   64
#define DMODEL 1024
#define BATCH  2
#define MROWS  4096   // B*T
#define L_CHK  64
#define N_CHK  (T_LEN / L_CHK)   // 32
#define BH     (BATCH * NHEAD)   // 32
#define LSTR   72                // padded LDS row stride (shorts); 144B = 16B-mult

typedef __attribute__((ext_vector_type(8))) short short8;
typedef __attribute__((ext_vector_type(4))) float f32x4;
typedef __attribute__((ext_vector_type(4))) unsigned short ushort4v;

// async global->LDS, 16B per lane; LDS dest = wave-uniform base + lane*16
#define GLDS(GP, LP) __builtin_amdgcn_global_load_lds( \
    (__attribute__((address_space(1))) void*)(void*)(GP), \
    (__attribute__((address_space(3))) void*)(LP), 16, 0, 0)

__device__ __forceinline__ unsigned short f2bf(float f) {
  union { float f; unsigned int u; } v; v.f = f;
  unsigned int r = v.u + 0x7FFFu + ((v.u >> 16) & 1u);   // RNE
  return (unsigned short)(r >> 16);
}
__device__ __forceinline__ float bf2f(short s) {
  union { unsigned int u; float f; } v;
  v.u = ((unsigned int)(unsigned short)s) << 16;
  return v.f;
}

// ---------------------------------------------------------------------------
// Weight transposes + x conversion in one launch: grid (16,16,5).
// ---------------------------------------------------------------------------
__global__ __launch_bounds__(256) void ha_conv(
    const float* __restrict__ Wq, const float* __restrict__ Wa,
    const float* __restrict__ Wb, const float* __restrict__ Wo,
    const float* __restrict__ X,
    short* __restrict__ wqabT, short* __restrict__ woT,
    short* __restrict__ Xb) {
  const int z = blockIdx.z;
  const int tid = threadIdx.x;
  if (z == 4) {   // x conversion: 256 blocks x 16384 floats
    const int bidl = blockIdx.y * 16 + blockIdx.x;
    #pragma unroll
    for (int p = 0; p < 8; ++p) {
      const size_t idx = (size_t)bidl * 16384 + (size_t)p * 2048 + tid * 8;
      float4 v0 = *(const float4*)(X + idx);
      float4 v1 = *(const float4*)(X + idx + 4);
      short8 o;
      o[0] = (short)f2bf(v0.x); o[1] = (short)f2bf(v0.y);
      o[2] = (short)f2bf(v0.z); o[3] = (short)f2bf(v0.w);
      o[4] = (short)f2bf(v1.x); o[5] = (short)f2bf(v1.y);
      o[6] = (short)f2bf(v1.z); o[7] = (short)f2bf(v1.w);
      *(short8*)(Xb + idx) = o;
    }
    return;
  }
  __shared__ float tile[64][65];
  const float* W = (z == 0) ? Wq : (z == 1) ? Wa : (z == 2) ? Wb : Wo;
  short* WT = (z < 3) ? wqabT + (size_t)z * 1024 * DMODEL : woT;
  const int k0 = blockIdx.y * 64, n0 = blockIdx.x * 64;
  #pragma unroll
  for (int p = 0; p < 4; ++p) {
    const int r  = p * 16 + (tid >> 4);
    const int c4 = (tid & 15) * 4;
    float4 v = *(const float4*)(W + (size_t)(k0 + r) * DMODEL + n0 + c4);
    tile[r][c4 + 0] = v.x; tile[r][c4 + 1] = v.y;
    tile[r][c4 + 2] = v.z; tile[r][c4 + 3] = v.w;
  }
  __syncthreads();
  #pragma unroll
  for (int p = 0; p < 4; ++p) {
    const int n = p * 16 + (tid >> 4);
    const int c = (tid & 15) * 4;
    ushort4v o = { f2bf(tile[c + 0][n]), f2bf(tile[c + 1][n]),
                   f2bf(tile[c + 2][n]), f2bf(tile[c + 3][n]) };
    *(ushort4v*)(WT + (size_t)(n0 + n) * DMODEL + k0 + c) = o;
  }
}

// ---------------------------------------------------------------------------
// Fused QAB projection GEMM + per-head LayerNorm epilogue, bf16 out.
// Linear LDS layout, scalar epilogue stores (r7-proven 43.9 us).
// r10 lesson: staged-store epilogue (+17KB LDS, +32 VGPR) cut occupancy
// 25->15% and cost +20 us — scalar stores overlap fine at high occupancy.
// ---------------------------------------------------------------------------
__global__ __launch_bounds__(256) void ha_gemm_qab(
    const short* __restrict__ Ab, const short* __restrict__ Bt,
    short* __restrict__ q, short* __restrict__ a, short* __restrict__ bOut,
    const float* __restrict__ qg, const float* __restrict__ qbet,
    const float* __restrict__ ag, const float* __restrict__ abet,
    const float* __restrict__ bg, const float* __restrict__ bbet) {
  __shared__ short As[128 * 32] __attribute__((aligned(16)));
  __shared__ short Bs[128 * 32] __attribute__((aligned(16)));
  const int tid = threadIdx.x;
  const int wave = tid >> 6, lane = tid & 63;
  const int m0  = blockIdx.y * 128;
  const int n0g = blockIdx.x * 128;           // [0, 3072)
  short* Cbuf; const float* gamma; const float* beta;
  if (n0g < 1024)      { Cbuf = q;    gamma = qg; beta = qbet; }
  else if (n0g < 2048) { Cbuf = a;    gamma = ag; beta = abet; }
  else                 { Cbuf = bOut; gamma = bg; beta = bbet; }
  const int n0 = n0g & 1023;

  const int srow = wave * 32 + (lane >> 2);
  const int scol = (lane & 3) * 8;
  const short* agp = Ab + (size_t)(m0 + srow) * DMODEL + scol;
  const short* bgp = Bt + (size_t)(n0g + srow) * DMODEL + scol;
  short* alp = As + wave * 32 * 32;
  short* blp = Bs + wave * 32 * 32;

  f32x4 acc[4][4] = {};
  const int lm = lane & 15, kh = lane >> 4;
  const int wm = (wave >> 1) * 64, wn = (wave & 1) * 64;

  float gl[4], bl[4];
  #pragma unroll
  for (int j = 0; j < 4; ++j) {
    gl[j] = gamma[j * 16 + lm];
    bl[j] = beta[j * 16 + lm];
  }

  for (int k0 = 0; k0 < DMODEL; k0 += 32) {
    GLDS(agp,               alp);
    GLDS(agp + 16 * DMODEL, alp + 16 * 32);
    GLDS(bgp,               blp);
    GLDS(bgp + 16 * DMODEL, blp + 16 * 32);
    agp += 32; bgp += 32;
    __syncthreads();
    short8 af[4], bf[4];
    #pragma unroll
    for (int i = 0; i < 4; ++i) {
      af[i] = *(const short8*)&As[(wm + i * 16 + lm) * 32 + kh * 8];
      bf[i] = *(const short8*)&Bs[(wn + i * 16 + lm) * 32 + kh * 8];
    }
    #pragma unroll
    for (int i = 0; i < 4; ++i)
      #pragma unroll
      for (int j = 0; j < 4; ++j)
        acc[i][j] = __builtin_amdgcn_mfma_f32_16x16x32_bf16(
            af[i], bf[j], acc[i][j], 0, 0, 0);
    __syncthreads();
  }

  // ---- fused LayerNorm epilogue (per output row within the head group) ----
  #pragma unroll
  for (int i = 0; i < 4; ++i) {
    float s1[4] = {0.f, 0.f, 0.f, 0.f};
    float s2[4] = {0.f, 0.f, 0.f, 0.f};
    #pragma unroll
    for (int j = 0; j < 4; ++j)
      #pragma unroll
      for (int r = 0; r < 4; ++r) {
        const float v = acc[i][j][r];
        s1[r] += v; s2[r] += v * v;
      }
    #pragma unroll
    for (int m = 1; m <= 8; m <<= 1)
      #pragma unroll
      for (int r = 0; r < 4; ++r) {
        s1[r] += __shfl_xor(s1[r], m);
        s2[r] += __shfl_xor(s2[r], m);
      }
    #pragma unroll
    for (int r = 0; r < 4; ++r) {
      const float mean = s1[r] * 0.015625f;
      const float var  = s2[r] * 0.015625f - mean * mean;
      const float rs   = rsqrtf(var + 1e-5f);
      short* cp = Cbuf + (size_t)(m0 + wm + i * 16 + kh * 4 + r) * DMODEL +
                  n0 + wn + lm;
      #pragma unroll
      for (int j = 0; j < 4; ++j)
        cp[j * 16] = (short)f2bf((acc[i][j][r] - mean) * rs * gl[j] + bl[j]);
    }
  }
}

// ---------------------------------------------------------------------------
// Output GEMM: C[M,1024] = Ob[M,1024](bf16) @ WoT[1024,1024]^T (linear LDS)
// ---------------------------------------------------------------------------
__global__ __launch_bounds__(256) void ha_gemm_out(
    const short* __restrict__ Ab, const short* __restrict__ Bt,
    float* __restrict__ C) {
  __shared__ short As[128 * 32] __attribute__((aligned(16)));
  __shared__ short Bs[64 * 32] __attribute__((aligned(16)));
  const int tid = threadIdx.x;
  const int wave = tid >> 6, lane = tid & 63;
  const int m0 = blockIdx.y * 128;
  const int n0 = blockIdx.x * 64;

  const int arow = wave * 32 + (lane >> 2);
  const int brow = wave * 16 + (lane >> 2);
  const int scol = (lane & 3) * 8;
  const short* agp = Ab + (size_t)(m0 + arow) * DMODEL + scol;
  const short* bgp = Bt + (size_t)(n0 + brow) * DMODEL + scol;
  short* alp = As + wave * 32 * 32;
  short* blp = Bs + wave * 16 * 32;

  f32x4 acc[4][2] = {};
  const int lm = lane & 15, kh = lane >> 4;
  const int wm = (wave >> 1) * 64, wn = (wave & 1) * 32;

  for (int k0 = 0; k0 < DMODEL; k0 += 32) {
    GLDS(agp,               alp);
    GLDS(agp + 16 * DMODEL, alp + 16 * 32);
    GLDS(bgp,               blp);
    agp += 32; bgp += 32;
    __syncthreads();
    short8 af[4], bf2[2];
    #pragma unroll
    for (int i = 0; i < 4; ++i)
      af[i] = *(const short8*)&As[(wm + i * 16 + lm) * 32 + kh * 8];
    #pragma unroll
    for (int j = 0; j < 2; ++j)
      bf2[j] = *(const short8*)&Bs[(wn + j * 16 + lm) * 32 + kh * 8];
    #pragma unroll
    for (int i = 0; i < 4; ++i)
      #pragma unroll
      for (int j = 0; j < 2; ++j)
        acc[i][j] = __builtin_amdgcn_mfma_f32_16x16x32_bf16(
            af[i], bf2[j], acc[i][j], 0, 0, 0);
    __syncthreads();
  }
  #pragma unroll
  for (int i = 0; i < 4; ++i)
    #pragma unroll
    for (int j = 0; j < 2; ++j) {
      float* cp = C + (size_t)(m0 + wm + i * 16 + kh * 4) * DMODEL +
                  n0 + wn + j * 16 + lm;
      #pragma unroll
      for (int r = 0; r < 4; ++r) cp[(size_t)r * DMODEL] = acc[i][j][r];
    }
}

// ---------------------------------------------------------------------------
// Scan pass 1 (MFMA): per (bh,c): Bt[e][s] staged transposed; L^T[d][s] =
// local-exclusive cumsum of a (bf16); M[e][d] = Bt·L^T via mfma (K=s).
// M written bf16 (s2p accumulates fp32). Also emits Asums/Bsums.
// ---------------------------------------------------------------------------
__global__ __launch_bounds__(256) void ha_scan1(
    const short* __restrict__ An, const short* __restrict__ Bn,
    short* __restrict__ M, float* __restrict__ Asums, float* __restrict__ Bsums) {
  __shared__ short Btl[64 * LSTR] __attribute__((aligned(16)));
  __shared__ short Ltl[64 * LSTR] __attribute__((aligned(16)));
  __shared__ float sega[4][64];
  __shared__ float segb[4][64];
  const int bid = blockIdx.x;
  const int c   = bid & (N_CHK - 1);
  const int bh  = bid >> 5;
  const int b = bh >> 4, h = bh & 15;
  const int tid = threadIdx.x;
  const size_t rowbase = ((size_t)b * T_LEN + (size_t)c * L_CHK) * DMODEL + h * HDIM;
  const size_t vec = ((size_t)bh * N_CHK + c) * 64;

  // stage B transposed: Btl[e][s]
  #pragma unroll
  for (int i = 0; i < 2; ++i) {
    const int idx = tid + 256 * i;
    const int s = idx >> 3, c8 = (idx & 7) * 8;
    short8 b8 = *(const short8*)(Bn + rowbase + (size_t)s * DMODEL + c8);
    #pragma unroll
    for (int k = 0; k < 8; ++k) Btl[(c8 + k) * LSTR + s] = b8[k];
  }

  const int d = tid & 63, seg = tid >> 6;
  {
    float run = 0.f;
    for (int s = seg * 16; s < seg * 16 + 16; ++s) {
      const float v = bf2f(An[rowbase + (size_t)s * DMODEL + d]);
      Ltl[d * LSTR + s] = (short)f2bf(run);
      run += v;
    }
    sega[seg][d] = run;
  }
  __syncthreads();
  {
    float off = 0.f;
    for (int qq = 0; qq < seg; ++qq) off += sega[qq][d];
    #pragma unroll
    for (int g = 0; g < 2; ++g) {
      short8 v = *(short8*)&Ltl[d * LSTR + seg * 16 + g * 8];
      #pragma unroll
      for (int k = 0; k < 8; ++k) v[k] = (short)f2bf(bf2f(v[k]) + off);
      *(short8*)&Ltl[d * LSTR + seg * 16 + g * 8] = v;
    }
    if (seg == 3) Asums[vec + d] = off + sega[3][d];
    float sb = 0.f;
    #pragma unroll
    for (int g = 0; g < 2; ++g) {
      short8 v = *(const short8*)&Btl[d * LSTR + seg * 16 + g * 8];
      #pragma unroll
      for (int k = 0; k < 8; ++k) sb += bf2f(v[k]);
    }
    segb[seg][d] = sb;
  }
  __syncthreads();
  if (tid < 64)
    Bsums[vec + tid] = segb[0][tid] + segb[1][tid] + segb[2][tid] + segb[3][tid];

  // M[e][d] = sum_s Btl[e][s] * Ltl[d][s]; wave owns 16-row e-strip
  const int wave = tid >> 6, lane = tid & 63;
  const int lm = lane & 15, quad = lane >> 4;
  const int estrip = wave * 16;
  f32x4 acc[4] = {};
  #pragma unroll
  for (int kk = 0; kk < 2; ++kk) {
    short8 afr = *(const short8*)&Btl[(estrip + lm) * LSTR + kk * 32 + quad * 8];
    #pragma unroll
    for (int j = 0; j < 4; ++j) {
      short8 bfr = *(const short8*)&Ltl[(j * 16 + lm) * LSTR + kk * 32 + quad * 8];
      acc[j] = __builtin_amdgcn_mfma_f32_16x16x32_bf16(afr, bfr, acc[j], 0, 0, 0);
    }
  }
  short* Mp = M + vec * 64;
  #pragma unroll
  for (int j = 0; j < 4; ++j)
    #pragma unroll
    for (int r = 0; r < 4; ++r)
      Mp[(estrip + quad * 4 + r) * 64 + j * 16 + lm] = (short)f2bf(acc[j][r]);
}

// ---------------------------------------------------------------------------
// Parallel S-prefix: Aoff prefix in LDS (part-0 exports), exclusive S prefix
// over chunks with depth-2 prefetch; M read bf16; Soff written bf16.
// ---------------------------------------------------------------------------
__global__ __launch_bounds__(256) void ha_s2p(
    const short* __restrict__ M, const float* __restrict__ Asums,
    const float* __restrict__ Bsums, float* __restrict__ Aoff,
    short* __restrict__ Soffb) {
  __shared__ float ao[N_CHK][64];   // 8 KB
  const int part = blockIdx.x & 7;
  const int bh   = blockIdx.x >> 3;
  const int tid  = threadIdx.x;
  for (int i = tid; i < N_CHK * 64; i += 256)
    ao[i >> 6][i & 63] = Asums[(size_t)bh * N_CHK * 64 + i];
  __syncthreads();
  if (tid < 64) {
    float run = 0.f;
    for (int c = 0; c < N_CHK; ++c) {
      const float v = ao[c][tid];
      ao[c][tid] = run;
      run += v;
    }
  }
  __syncthreads();
  if (part == 0)
    for (int i = tid; i < N_CHK * 64; i += 256)
      Aoff[(size_t)bh * N_CHK * 64 + i] = ao[i >> 6][i & 63];

  const int e = part * 8 + (tid >> 5);
  const int d = (tid & 31) * 2;
  float2 S = make_float2(0.f, 0.f);
  const short* Mp = M + (size_t)bh * N_CHK * 4096 + e * 64 + d;
  const float* Bp = Bsums + (size_t)bh * N_CHK * 64 + e;
  short* Sp = Soffb + (size_t)bh * N_CHK * 4096 + e * 64 + d;
  unsigned mr0 = *(const unsigned*)Mp;
  unsigned mr1 = *(const unsigned*)(Mp + 4096);
  float bs0 = Bp[0], bs1 = Bp[64];
  for (int c = 0; c < N_CHK; ++c) {
    const int c2 = (c + 2 < N_CHK) ? c + 2 : c;
    const unsigned mrn = *(const unsigned*)(Mp + (size_t)c2 * 4096);
    const float bsn = Bp[(size_t)c2 * 64];
    const unsigned pk = (unsigned)f2bf(S.x) | ((unsigned)f2bf(S.y) << 16);
    *(unsigned*)(Sp + (size_t)c * 4096) = pk;
    S.x += fmaf(bs0, ao[c][d],     bf2f((short)(mr0 & 0xffffu)));
    S.y += fmaf(bs0, ao[c][d + 1], bf2f((short)(mr0 >> 16)));
    mr0 = mr1; mr1 = mrn; bs0 = bs1; bs1 = bsn;
  }
}

// ---------------------------------------------------------------------------
// Scan pass 3 (MFMA): P = Q·G^T (bf16), causal mask, O = Pt·B^T + Q·Soff^T.
// O restaged through Gs (dead after P phase) -> 16B vector stores.
// ---------------------------------------------------------------------------
__global__ __launch_bounds__(256) void ha_scan3(
    const short* __restrict__ Qn, const short* __restrict__ An,
    const short* __restrict__ Bn, const short* __restrict__ Soffb,
    const float* __restrict__ Aoff, short* __restrict__ Ob) {
  __shared__ short Qs [64 * LSTR] __attribute__((aligned(16)));
  __shared__ short Gs [64 * LSTR] __attribute__((aligned(16)));
  __shared__ short Btl[64 * LSTR] __attribute__((aligned(16)));
  __shared__ short Ssl[64 * LSTR] __attribute__((aligned(16)));
  __shared__ short Ptl[64 * LSTR] __attribute__((aligned(16)));
  __shared__ float sega[4][64];
  const int bid = blockIdx.x;
  const int c   = bid & (N_CHK - 1);
  const int bh  = bid >> 5;
  const int b = bh >> 4, h = bh & 15;
  const int tid = threadIdx.x;
  const size_t rowbase = ((size_t)b * T_LEN + (size_t)c * L_CHK) * DMODEL + h * HDIM;
  const size_t vec = ((size_t)bh * N_CHK + c) * 64;

  #pragma unroll
  for (int i = 0; i < 2; ++i) {
    const int idx = tid + 256 * i;
    const int r = idx >> 3, c8 = (idx & 7) * 8;
    short8 q8 = *(const short8*)(Qn + rowbase + (size_t)r * DMODEL + c8);
    *(short8*)&Qs[r * LSTR + c8] = q8;
    short8 s8 = *(const short8*)(Soffb + vec * 64 + (size_t)r * 64 + c8);
    *(short8*)&Ssl[r * LSTR + c8] = s8;
    short8 b8 = *(const short8*)(Bn + rowbase + (size_t)r * DMODEL + c8);
    #pragma unroll
    for (int k = 0; k < 8; ++k) Btl[(c8 + k) * LSTR + r] = b8[k];
  }

  const int d = tid & 63, seg = tid >> 6;
  {
    float run = 0.f;
    for (int s = seg * 16; s < seg * 16 + 16; ++s) {
      const float v = bf2f(An[rowbase + (size_t)s * DMODEL + d]);
      Gs[s * LSTR + d] = (short)f2bf(run);
      run += v;
    }
    sega[seg][d] = run;
  }
  __syncthreads();
  {
    float off = Aoff[vec + d];
    for (int qq = 0; qq < seg; ++qq) off += sega[qq][d];
    for (int s = seg * 16; s < seg * 16 + 16; ++s)
      Gs[s * LSTR + d] = (short)f2bf(bf2f(Gs[s * LSTR + d]) + off);
  }
  __syncthreads();

  const int wave = tid >> 6, lane = tid & 63;
  const int lm = lane & 15, quad = lane >> 4;
  const int tstrip = wave * 16;
  {
    f32x4 p[4] = {};
    #pragma unroll
    for (int kk = 0; kk < 2; ++kk) {
      short8 qf = *(const short8*)&Qs[(tstrip + lm) * LSTR + kk * 32 + quad * 8];
      #pragma unroll
      for (int j = 0; j < 4; ++j) {
        short8 gf = *(const short8*)&Gs[(j * 16 + lm) * LSTR + kk * 32 + quad * 8];
        p[j] = __builtin_amdgcn_mfma_f32_16x16x32_bf16(qf, gf, p[j], 0, 0, 0);
      }
    }
    #pragma unroll
    for (int j = 0; j < 4; ++j)
      #pragma unroll
      for (int r = 0; r < 4; ++r) {
        const int t = tstrip + quad * 4 + r;
        const int s = j * 16 + lm;
        Ptl[t * LSTR + s] = (s <= t) ? (short)f2bf(p[j][r]) : (short)0;
      }
  }
  __syncthreads();

  {
    f32x4 o[4] = {};
    #pragma unroll
    for (int kk = 0; kk < 2; ++kk) {
      short8 pf = *(const short8*)&Ptl[(tstrip + lm) * LSTR + kk * 32 + quad * 8];
      #pragma unroll
      for (int j = 0; j < 4; ++j) {
        short8 bfr = *(const short8*)&Btl[(j * 16 + lm) * LSTR + kk * 32 + quad * 8];
        o[j] = __builtin_amdgcn_mfma_f32_16x16x32_bf16(pf, bfr, o[j], 0, 0, 0);
      }
    }
    #pragma unroll
    for (int kk = 0; kk < 2; ++kk) {
      short8 qf = *(const short8*)&Qs[(tstrip + lm) * LSTR + kk * 32 + quad * 8];
      #pragma unroll
      for (int j = 0; j < 4; ++j) {
        short8 sf = *(const short8*)&Ssl[(j * 16 + lm) * LSTR + kk * 32 + quad * 8];
        o[j] = __builtin_amdgcn_mfma_f32_16x16x32_bf16(qf, sf, o[j], 0, 0, 0);
      }
    }
    // restage O bf16 into Gs (free after P phase), [t][e]
    #pragma unroll
    for (int j = 0; j < 4; ++j)
      #pragma unroll
      for (int r = 0; r < 4; ++r)
        Gs[(tstrip + quad * 4 + r) * LSTR + j * 16 + lm] = (short)f2bf(o[j][r]);
  }
  __syncthreads();
  {
    const int t = tid >> 2, seg2 = tid & 3;   // 64 rows x 4 segs x 16 shorts
    short8 v0 = *(const short8*)&Gs[t * LSTR + seg2 * 16];
    short8 v1 = *(const short8*)&Gs[t * LSTR + seg2 * 16 + 8];
    short* op = Ob + rowbase + (size_t)t * DMODEL + seg2 * 16;
    *(short8*)op       = v0;
    *(short8*)(op + 8) = v1;
  }
}

// ---------------------------------------------------------------------------
extern "C" void kernel_launch(void* const* d_in, const int* in_sizes, int n_in,
                              void* d_out, int out_size, void* d_ws,
                              size_t ws_size, hipStream_t stream) {
  const float* x  = (const float*)d_in[0];
  const float* Wq = (const float*)d_in[1];
  const float* Wa = (const float*)d_in[2];
  const float* Wb = (const float*)d_in[3];
  const float* Wo = (const float*)d_in[4];
  const float* qg = (const float*)d_in[5];
  const float* qb = (const float*)d_in[6];
  const float* ag = (const float*)d_in[7];
  const float* ab = (const float*)d_in[8];
  const float* bg = (const float*)d_in[9];
  const float* bb = (const float*)d_in[10];
  float* out = (float*)d_out;

  // workspace layout (~50 MB of the 64 MB proven available):
  char* ws = (char*)d_ws;
  short* qn  = (short*)(ws);                          // [0,8) MB bf16
  short* an  = (short*)(ws + ((size_t)8  << 20));     // [8,16) MB
  short* bn  = (short*)(ws + ((size_t)16 << 20));     // [16,24) MB
  short* xb  = (short*)(ws + ((size_t)24 << 20));     // [24,32) MB
  short* obb = xb;                                    // overlay: xb dead after QAB GEMM
  short* wqabT = (short*)(ws + ((size_t)32 << 20));   // [32,38) MB
  short* woT   = (short*)(ws + ((size_t)38 << 20));   // [38,40) MB
  float* asums = (float*)(ws + ((size_t)40 << 20));   // 256 KB
  float* bsums = asums + (size_t)BH * N_CHK * 64;     // 256 KB
  float* aoff  = bsums + (size_t)BH * N_CHK * 64;     // 256 KB
  short* soffb = (short*)(ws + ((size_t)42 << 20));   // [42,50) MB bf16 Soff
  short* Mbuf  = (short*)out;  // d_out doubles as bf16 Mlocal scratch (8 MB)

  ha_conv<<<dim3(16, 16, 5), 256, 0, stream>>>(Wq, Wa, Wb, Wo, x,
                                               wqabT, woT, xb);

  ha_gemm_qab<<<dim3(24, 32), 256, 0, stream>>>(xb, wqabT, qn, an, bn,
                                                qg, qb, ag, ab, bg, bb);

  ha_scan1<<<BH * N_CHK, 256, 0, stream>>>(an, bn, Mbuf, asums, bsums);
  ha_s2p<<<BH * 8, 256, 0, stream>>>(Mbuf, asums, bsums, aoff, soffb);
  ha_scan3<<<BH * N_CHK, 256, 0, stream>>>(qn, an, bn, soffb, aoff, obb);

  ha_gemm_out<<<dim3(16, 32), 256, 0, stream>>>(obb, woT, out);
}